// Round 8
// baseline (412.737 us; speedup 1.0000x reference)
//
#include <hip/hip_runtime.h>
#include <cstdint>

typedef unsigned int u32;
typedef unsigned short u16;
typedef float fx4 __attribute__((ext_vector_type(4)));
typedef __bf16 bfx8 __attribute__((ext_vector_type(8)));

// ---------- helpers ----------
__device__ __forceinline__ u16 f2bf(float f) {
  u32 u = __builtin_bit_cast(u32, f);
  u32 r = (u + 0x7fffu + ((u >> 16) & 1u)) >> 16;  // RNE
  return (u16)r;
}
__device__ __forceinline__ float bf2f(u16 v) {
  return __builtin_bit_cast(float, (u32)v << 16);
}
// async global->LDS, 16B per lane (gfx950). LDS dest = wave-uniform base + lane*16.
__device__ __forceinline__ void async_copy16(const void* g, void* l) {
  auto gp = reinterpret_cast<__attribute__((address_space(1))) void*>((uintptr_t)g);
  auto lp = reinterpret_cast<__attribute__((address_space(3))) void*>((uintptr_t)l);
  __builtin_amdgcn_global_load_lds(gp, lp, 16, 0, 0);
}

// ---------- fp32 -> bf16 conversion of x, c, 8 weights ----------
__global__ __launch_bounds__(256) void cvt_all(
    const float* __restrict__ x, const float* __restrict__ c,
    const float* __restrict__ w0, const float* __restrict__ w1,
    const float* __restrict__ w2, const float* __restrict__ w3,
    const float* __restrict__ w4, const float* __restrict__ w5,
    const float* __restrict__ w6, const float* __restrict__ w7,
    u16* __restrict__ xb, u16* __restrict__ cb, u16* __restrict__ wb) {
  const int i = blockIdx.x * 256 + threadIdx.x;  // float4 index
  const float* src;
  u16* dst;
  size_t off;
  if (i < 4194304) {            // x: 16777216 floats
    src = x; dst = xb; off = (size_t)i;
  } else if (i < 4456448) {     // c: 1048576 floats
    src = c; dst = cb; off = (size_t)(i - 4194304);
  } else {                      // 8 weights, 1048576 floats each
    const int r = i - 4456448;
    const int wsel = r >> 18;
    off = (size_t)(r & 262143);
    switch (wsel) {
      case 0: src = w0; break; case 1: src = w1; break;
      case 2: src = w2; break; case 3: src = w3; break;
      case 4: src = w4; break; case 5: src = w5; break;
      case 6: src = w6; break; default: src = w7; break;
    }
    dst = wb + (size_t)wsel * 1048576;
  }
  const fx4 v = *(const fx4*)(src + off * 4);
  uint2 o;
  o.x = (u32)f2bf(v[0]) | ((u32)f2bf(v[1]) << 16);
  o.y = (u32)f2bf(v[2]) | ((u32)f2bf(v[3]) << 16);
  *(uint2*)(dst + off * 4) = o;
}

// ---------- 256x256 tile GEMM core, K=1024, BK=32, 8 waves, 64KB LDS ----------
// One phase per K-tile: {stage tile tt+1 (4 loads) || 12 ds_read -> barrier ->
// lgkm(0) -> setprio 32 MFMA -> vmcnt(0) [issued ~1200cyc earlier] -> barrier}.
// Half the barriers of the R6 8-phase structure at the same LDS-bytes/MFMA.
// Region format (R4-verified): 256 rows x 32 k packed 2 rows per 128B LDS row,
// 8-chunk XOR swizzle via pre-swizzled global source.
#define GC2_DS()                                                               \
  _Pragma("unroll") for (int i_ = 0; i_ < 4; ++i_) bfr[i_] =                   \
      *(const bfx8*)(lds + bufo + 8192 + wc * 2048 + i_ * 512 + aLane);        \
  _Pragma("unroll") for (int i_ = 0; i_ < 4; ++i_) af0[i_] =                   \
      *(const bfx8*)(lds + bufo + wr * 4096 + i_ * 512 + aLane);               \
  _Pragma("unroll") for (int i_ = 0; i_ < 4; ++i_) af1[i_] =                   \
      *(const bfx8*)(lds + bufo + wr * 4096 + 2048 + i_ * 512 + aLane);
#define GC2_ST(BUF, KT)                                                        \
  async_copy16(Aop + aOff0 + (KT) * 32, lds + (BUF) + dst0);                   \
  async_copy16(Aop + aOff1 + (KT) * 32, lds + (BUF) + dst1);                   \
  async_copy16(Bop + bOff0 + (KT) * 32, lds + (BUF) + 8192 + dst0);            \
  async_copy16(Bop + bOff1 + (KT) * 32, lds + (BUF) + 8192 + dst1);

__device__ __forceinline__ void gemm256_core(
    const u16* __restrict__ Aop, const u16* __restrict__ Bop,
    long rowBase, long colBase, u16* lds, fx4 (&acc)[8][4]) {
  const int t = threadIdx.x;           // 0..511
  const int lane = t & 63;
  const int lr = lane & 15;
  const int quad = lane >> 4;
  const int w = t >> 6;                // 0..7
  const int wr = w >> 2;               // 0..1  (M half)
  const int wc = w & 3;                // 0..3  (N quarter)
  const int phys = (((lr & 1) << 2) | quad) ^ ((lr >> 1) & 7);
  const int aLane = ((lr >> 1) << 6) + (phys << 3);

  // staging inverse-swizzle map: chunks c = t, t+512 of a 16KB region
  int aOff0, aOff1, bOff0, bOff1, dst0, dst1;
  {
    const int c0 = t;
    const int R0 = c0 >> 3;
    const int lg0 = (c0 & 7) ^ (R0 & 7);
    const int m0_ = 2 * R0 + (lg0 >> 2);
    const int g0 = lg0 & 3;
    aOff0 = (int)(rowBase + m0_) * 1024 + g0 * 8;
    bOff0 = (int)(colBase + m0_) * 1024 + g0 * 8;
    dst0 = c0 * 8;
    const int c1 = t + 512;
    const int R1 = c1 >> 3;
    const int lg1 = (c1 & 7) ^ (R1 & 7);
    const int m1_ = 2 * R1 + (lg1 >> 2);
    const int g1 = lg1 & 3;
    aOff1 = (int)(rowBase + m1_) * 1024 + g1 * 8;
    bOff1 = (int)(colBase + m1_) * 1024 + g1 * 8;
    dst1 = c1 * 8;
  }

  // prologue: stage tile 0 into buffer 0
  GC2_ST(0, 0)
  asm volatile("s_waitcnt vmcnt(0)" ::: "memory");
  __builtin_amdgcn_s_barrier();
  __builtin_amdgcn_sched_barrier(0);

  for (int tt = 0; tt < 32; ++tt) {
    const int bufo = (tt & 1) << 14;        // 16384 u16 per buffer
    const int nbuf = ((tt + 1) & 1) << 14;
    bfx8 af0[4], af1[4], bfr[4];
    // issue next tile's stage FIRST (max latency headroom), then frag reads
    if (tt < 31) { GC2_ST(nbuf, tt + 1) }
    GC2_DS()
    __builtin_amdgcn_s_barrier();
    asm volatile("s_waitcnt lgkmcnt(0)" ::: "memory");
    __builtin_amdgcn_sched_barrier(0);
    __builtin_amdgcn_s_setprio(1);
#pragma unroll
    for (int mi = 0; mi < 4; ++mi)
#pragma unroll
      for (int ni = 0; ni < 4; ++ni)
        acc[mi][ni] =
            __builtin_amdgcn_mfma_f32_16x16x32_bf16(af0[mi], bfr[ni], acc[mi][ni], 0, 0, 0);
#pragma unroll
    for (int mi = 0; mi < 4; ++mi)
#pragma unroll
      for (int ni = 0; ni < 4; ++ni)
        acc[4 + mi][ni] =
            __builtin_amdgcn_mfma_f32_16x16x32_bf16(af1[mi], bfr[ni], acc[4 + mi][ni], 0, 0, 0);
    __builtin_amdgcn_s_setprio(0);
    __builtin_amdgcn_sched_barrier(0);
    if (tt < 31) { asm volatile("s_waitcnt vmcnt(0)" ::: "memory"); }
    __builtin_amdgcn_s_barrier();
    __builtin_amdgcn_sched_barrier(0);
  }
}

// ---------- fused projections: all 6 QKV GEMMs in one dispatch ----------
// XCD chunked swizzle (816 % 8 == 0, bijective), A-panel-major order.
__global__ __launch_bounds__(512, 2) void proj_fused(
    const u16* __restrict__ Xb, const u16* __restrict__ Cb, const u16* __restrict__ Wb,
    u16* __restrict__ Qx, u16* __restrict__ Qc,
    u16* __restrict__ Kt, u16* __restrict__ Vt,
    const float* __restrict__ nc) {
  extern __shared__ __align__(16) u16 lds[];
  const int bid = (int)(blockIdx.y * 12 + blockIdx.x);
  const int u = (bid & 7) * 102 + (bid >> 3);
  const int yy = u / 12;
  const int xx = u - yy * 12;
  const bool isC = yy >= 64;
  const u16* A = isC ? Cb : Xb;
  const u16* Bw = Wb + (isC ? 3145728 : 0);  // c-stream weights at +3*1024*1024
  const long rowBase = (long)(isC ? yy - 64 : yy) * 256;
  const long colBase = (long)xx * 256;

  fx4 acc[8][4] = {};
  gemm256_core(A, Bw, rowBase, colBase, lds, acc);

  const int t = threadIdx.x;
  const int lane = t & 63;
  const int lr = lane & 15;
  const int quad = lane >> 4;
  const int w = t >> 6;
  const int wr = w >> 2;
  const int wc = w & 3;
  const long wRowBase = rowBase + wr * 128;

  const long col0 = colBase + wc * 64;   // 64-aligned: wave covers one head segment
  const int col64 = (int)(col0 >> 6);    // 0..47
  const int sel = col64 >> 4;            // 0=q, 1=k, 2=v  (uniform per block)
  const int h = col64 & 15;
  const int lcolBase = (int)(col0 & 1023);

  if (sel == 0) {
    // Q: per-row l2norm, row-major store (feeds out_fused A-operand)
    u16* dst = isC ? Qc : Qx;
#pragma unroll
    for (int mi = 0; mi < 8; ++mi) {
      float ss[4] = {0.f, 0.f, 0.f, 0.f};
#pragma unroll
      for (int ni = 0; ni < 4; ++ni)
#pragma unroll
        for (int r = 0; r < 4; ++r) ss[r] += acc[mi][ni][r] * acc[mi][ni][r];
#pragma unroll
      for (int off = 1; off < 16; off <<= 1)
#pragma unroll
        for (int r = 0; r < 4; ++r) ss[r] += __shfl_xor(ss[r], off, 64);
      float sc[4];
#pragma unroll
      for (int r = 0; r < 4; ++r) sc[r] = 1.f / fmaxf(sqrtf(ss[r]), 1e-12f);
#pragma unroll
      for (int ni = 0; ni < 4; ++ni) {
        const long col = lcolBase + ni * 16 + lr;
#pragma unroll
        for (int r = 0; r < 4; ++r) {
          const long row = wRowBase + mi * 16 + quad * 4 + r;
          dst[row * 1024 + col] = f2bf(acc[mi][ni][r] * sc[r]);
        }
      }
    }
  } else {
    // K (l2norm) / V (scale): per-wave LDS transpose -> Kt/Vt[b,h][d][0..4352)
    // 8KB/wave (fits 64KB LDS): two 64-col halves of the wave's 128 rows.
    u16* LT = lds + w * 4096;  // [d=64][64 n] u16, n-group ^ (d&7)
    u16* T = (sel == 1) ? Kt : Vt;
    int b, nglob0;
    if (!isC) { b = (int)(wRowBase >> 12); nglob0 = (int)(wRowBase & 4095); }
    else      { b = (int)(wRowBase >> 8);  nglob0 = 4096 + (int)(wRowBase & 255); }
    u16* Tw = T + (size_t)(b * 16 + h) * 64 * 4352;
    const float vs = __expf(-8.3783908f / (1.f + __expf(-nc[h])));  // 4352^-sigmoid
    const int d = lane;
    u16* drow = Tw + (size_t)d * 4352 + nglob0;

#pragma unroll
    for (int half = 0; half < 2; ++half) {
      __syncthreads();  // seal gemm LDS reads (half 0) / previous half's reads
#pragma unroll
      for (int mi2 = 0; mi2 < 4; ++mi2) {
        const int mi = half * 4 + mi2;
        float sc[4];
        if (sel == 1) {
          float ss[4] = {0.f, 0.f, 0.f, 0.f};
#pragma unroll
          for (int ni = 0; ni < 4; ++ni)
#pragma unroll
            for (int r = 0; r < 4; ++r) ss[r] += acc[mi][ni][r] * acc[mi][ni][r];
#pragma unroll
          for (int off = 1; off < 16; off <<= 1)
#pragma unroll
            for (int r = 0; r < 4; ++r) ss[r] += __shfl_xor(ss[r], off, 64);
#pragma unroll
          for (int r = 0; r < 4; ++r) sc[r] = 1.f / fmaxf(sqrtf(ss[r]), 1e-12f);
        } else {
#pragma unroll
          for (int r = 0; r < 4; ++r) sc[r] = vs;
        }
        const int g = mi2 * 2 + (quad >> 1);  // n-group within half
        const int sub = (quad & 1) * 4;
#pragma unroll
        for (int ni = 0; ni < 4; ++ni) {
          const int dd = ni * 16 + lr;
          uint2 o;
          o.x = (u32)f2bf(acc[mi][ni][0] * sc[0]) | ((u32)f2bf(acc[mi][ni][1] * sc[1]) << 16);
          o.y = (u32)f2bf(acc[mi][ni][2] * sc[2]) | ((u32)f2bf(acc[mi][ni][3] * sc[3]) << 16);
          *(uint2*)&LT[dd * 64 + ((g ^ (dd & 7)) << 3) + sub] = o;
        }
      }
      __syncthreads();  // uniform; orders LDS writes before drain
#pragma unroll
      for (int j = 0; j < 8; ++j) {
        const uint4 qv = *(const uint4*)&LT[d * 64 + ((j ^ (d & 7)) << 3)];
        *(uint4*)&drow[half * 64 + j * 8] = qv;
      }
    }
  }
}

// ---------- kv via MFMA, split-K partials (NO atomics) ----------
// grid (64, 17): block (bh, y) covers K-steps 4y..4y+3 (one 64-step per wave).
// Per-block 4-way LDS reduce, plain coalesced stores to kvp[y][bh].
__global__ __launch_bounds__(256) void kv_mfma(
    const u16* __restrict__ Kt, const u16* __restrict__ Vt, float* __restrict__ kvp) {
  __shared__ __align__(16) u16 TT[4][2][4096];  // per wave: K tile, V tile (64x64 u16)
  const int bh = blockIdx.x;
  const int t = threadIdx.x;
  const int w = t >> 6;
  const int lane = t & 63;
  const int lr = lane & 15;
  const int quad = lane >> 4;
  const u16* Ksrc = Kt + (size_t)bh * 64 * 4352;
  const u16* Vsrc = Vt + (size_t)bh * 64 * 4352;
  const int row8 = lane >> 3;
  const int gst = lane & 7;
  fx4 acc[4][4] = {};

  const int kbase = (blockIdx.y * 4 + w) * 64;  // this wave's K-step
#pragma unroll
  for (int i = 0; i < 8; ++i) {
    const int row = i * 8 + row8;
    const int col = ((gst ^ (row & 7)) << 3);
    const size_t go = (size_t)row * 4352 + kbase + col;
    async_copy16(Ksrc + go, &TT[w][0][i * 512 + lane * 8]);
    async_copy16(Vsrc + go, &TT[w][1][i * 512 + lane * 8]);
  }
  __syncthreads();
#pragma unroll
  for (int ks = 0; ks < 2; ++ks) {
    bfx8 af[4], bfr[4];
    const int g = ((ks * 4 + quad) ^ (lr & 7)) << 3;
#pragma unroll
    for (int i = 0; i < 4; ++i) af[i] = *(const bfx8*)&TT[w][0][(i * 16 + lr) * 64 + g];
#pragma unroll
    for (int i = 0; i < 4; ++i) bfr[i] = *(const bfx8*)&TT[w][1][(i * 16 + lr) * 64 + g];
#pragma unroll
    for (int mi = 0; mi < 4; ++mi)
#pragma unroll
      for (int ni = 0; ni < 4; ++ni)
        acc[mi][ni] =
            __builtin_amdgcn_mfma_f32_16x16x32_bf16(af[mi], bfr[ni], acc[mi][ni], 0, 0, 0);
  }
  __syncthreads();
  // per-wave partial C^T [e][d] f32, d-group swizzled; then 4-way reduce
  float* red = (float*)&TT[0][0][0];  // 16384 f32
  float* my = red + w * 4096;
#pragma unroll
  for (int mi = 0; mi < 4; ++mi)
#pragma unroll
    for (int ni = 0; ni < 4; ++ni) {
      const int e = ni * 16 + lr;
      const int dg = mi * 4 + quad;      // d = dg*4 + r, r consecutive in acc
      *(fx4*)&my[e * 64 + ((dg ^ (e & 15)) << 2)] = acc[mi][ni];
    }
  __syncthreads();
  float* outp = kvp + ((size_t)blockIdx.y * 64 + bh) * 4096;
#pragma unroll
  for (int j = 0; j < 4; ++j) {
    const int L = t * 16 + j * 4;        // flat [e][d] index
    const int e = L >> 6;
    const int dg = (L >> 2) & 15;
    const int addr = e * 64 + ((dg ^ (e & 15)) << 2);
    fx4 sv = *(const fx4*)&red[addr];
    sv += *(const fx4*)&red[4096 + addr];
    sv += *(const fx4*)&red[8192 + addr];
    sv += *(const fx4*)&red[12288 + addr];
    *(fx4*)&outp[L] = sv;
  }
}

// ---------- sum the 17 split-K partials: kvb[bh] = sum_y kvp[y][bh] ----------
__global__ __launch_bounds__(256) void kv_reduce(
    const float* __restrict__ kvp, float* __restrict__ kvb) {
  const int o = blockIdx.x * 256 + threadIdx.x;  // fx4 index, 65536 total
  const int bh = o >> 10;
  const int idx = (o & 1023) * 4;
  fx4 s = {0.f, 0.f, 0.f, 0.f};
#pragma unroll
  for (int y = 0; y < 17; ++y)
    s += *(const fx4*)&kvp[((size_t)y * 64 + bh) * 4096 + idx];
  *(fx4*)&kvb[(size_t)bh * 4096 + idx] = s;
}

// ---------- Weff[b][o, h*64+d] = sum_e Wo[o, h*64+e] * kv[b,h][d,e]  (bf16 out) ----------
// kvb holds kv transposed: kvb[bh][e*64+d].
__global__ __launch_bounds__(256) void weff_build(
    const u16* __restrict__ WoX, const u16* __restrict__ WoC,
    const float* __restrict__ kvb, u16* __restrict__ WeffX, u16* __restrict__ WeffC) {
  const int ot = blockIdx.x;
  const int bh = blockIdx.y;
  const int b = bh >> 4, h = bh & 15;
  const u16* Wo = blockIdx.z ? WoC : WoX;
  u16* outp = (blockIdx.z ? WeffC : WeffX) + (size_t)b * 1048576;

  __shared__ __align__(16) float kvT[64 * 64];  // [e][d] = kvb layout, direct copy
  __shared__ __align__(16) float WoT[64 * 64];  // [e][o_local]
  const int t = threadIdx.x;
#pragma unroll
  for (int j = 0; j < 4; ++j) {
    const int idx = (t + 256 * j) * 4;
    *(fx4*)&kvT[idx] = *(const fx4*)&kvb[(size_t)bh * 4096 + idx];
  }
#pragma unroll
  for (int j = 0; j < 2; ++j) {
    const int u = t + 256 * j;  // 512 groups of 8 bf16
    const int row = u >> 3;     // o_local
    const int e0 = (u & 7) * 8;
    const uint4 q = *(const uint4*)&Wo[(size_t)(ot * 64 + row) * 1024 + h * 64 + e0];
    WoT[(e0 + 0) * 64 + row] = bf2f((u16)(q.x & 0xffff));
    WoT[(e0 + 1) * 64 + row] = bf2f((u16)(q.x >> 16));
    WoT[(e0 + 2) * 64 + row] = bf2f((u16)(q.y & 0xffff));
    WoT[(e0 + 3) * 64 + row] = bf2f((u16)(q.y >> 16));
    WoT[(e0 + 4) * 64 + row] = bf2f((u16)(q.z & 0xffff));
    WoT[(e0 + 5) * 64 + row] = bf2f((u16)(q.z >> 16));
    WoT[(e0 + 6) * 64 + row] = bf2f((u16)(q.w & 0xffff));
    WoT[(e0 + 7) * 64 + row] = bf2f((u16)(q.w >> 16));
  }
  __syncthreads();
  const int ob = (t >> 4) * 4;  // o_local base
  const int db = (t & 15) * 4;  // d base
  float acc[4][4] = {};
#pragma unroll 4
  for (int e = 0; e < 64; ++e) {
    const fx4 wv = *(const fx4*)&WoT[e * 64 + ob];
    const fx4 kvv = *(const fx4*)&kvT[e * 64 + db];
#pragma unroll
    for (int i = 0; i < 4; ++i)
#pragma unroll
      for (int j = 0; j < 4; ++j)
        acc[i][j] += wv[i] * kvv[j];
  }
#pragma unroll
  for (int i = 0; i < 4; ++i)
#pragma unroll
    for (int j = 0; j < 4; ++j)
      outp[(size_t)(ot * 64 + ob + i) * 1024 + h * 64 + db + j] = f2bf(acc[i][j]);
}

// ---------- fused output GEMMs: out = q @ Weff[b]^T for x and c streams ----------
// XCD chunked swizzle: u = yt*4 + xx; u = (bid%8)*34 + bid/8 (272 % 8 == 0).
__global__ __launch_bounds__(512, 2) void out_fused(
    const u16* __restrict__ Qx, const u16* __restrict__ Qc,
    const u16* __restrict__ Wex, const u16* __restrict__ Wec,
    float* __restrict__ out) {
  extern __shared__ __align__(16) u16 lds[];
  const int bid = (int)(blockIdx.y * 4 + blockIdx.x);
  const int u = (bid & 7) * 34 + (bid >> 3);
  const int yt = u >> 2;
  const int xx = u & 3;
  const int b = yt / 17;
  const int l = yt - b * 17;
  const bool isC = (l == 16);
  const u16* A;
  const u16* Bw;
  float* C;
  long rowBase;
  if (!isC) {
    A = Qx + (size_t)b * 4194304;
    Bw = Wex + (size_t)b * 1048576;
    C = out + (size_t)b * 4194304;
    rowBase = (long)l * 256;
  } else {
    A = Qc + (size_t)b * 262144;
    Bw = Wec + (size_t)b * 1048576;
    C = out + 16777216 + (size_t)b * 262144;
    rowBase = 0;
  }
  const long colBase = (long)xx * 256;

  fx4 acc[8][4] = {};
  gemm256_core(A, Bw, rowBase, colBase, lds, acc);

  const int t = threadIdx.x;
  const int lane = t & 63;
  const int lr = lane & 15;
  const int quad = lane >> 4;
  const int w = t >> 6;
  const int wr = w >> 2;
  const int wc = w & 3;
#pragma unroll
  for (int mi = 0; mi < 8; ++mi)
#pragma unroll
    for (int ni = 0; ni < 4; ++ni) {
      const long col = colBase + wc * 64 + ni * 16 + lr;
#pragma unroll
      for (int r = 0; r < 4; ++r) {
        const long row = rowBase + wr * 128 + mi * 16 + quad * 4 + r;
        C[row * 1024 + col] = acc[mi][ni][r];
      }
    }
}

// ---------- launch ----------
extern "C" void kernel_launch(void* const* d_in, const int* in_sizes, int n_in,
                              void* d_out, int out_size, void* d_ws, size_t ws_size,
                              hipStream_t stream) {
  (void)in_sizes; (void)n_in; (void)out_size; (void)ws_size;
  const float* x = (const float*)d_in[0];
  const float* c = (const float*)d_in[1];
  const float* nc = (const float*)d_in[10];
  float* out = (float*)d_out;
  char* ws = (char*)d_ws;

  static bool attr_done = false;
  if (!attr_done) {
    hipFuncSetAttribute((const void*)proj_fused,
                        hipFuncAttributeMaxDynamicSharedMemorySize, 65536);
    hipFuncSetAttribute((const void*)out_fused,
                        hipFuncAttributeMaxDynamicSharedMemorySize, 65536);
    attr_done = true;
  }

  // workspace layout (bytes). total = 177,209,344
  u16* Xb = (u16*)(ws + 0);                 // 33,554,432
  u16* Cb = (u16*)(ws + 33554432);          //  2,097,152
  u16* Wb = (u16*)(ws + 35651584);          // 16,777,216 (8 weights bf16)
  u16* Qx = (u16*)(ws + 52428800);          // 33,554,432
  u16* Qc = (u16*)(ws + 85983232);          //  2,097,152
  u16* Kt = (u16*)(ws + 88080384);          // 35,651,584  [b,h][64 d][4352 n]
  u16* Vt = (u16*)(ws + 123731968);         // 35,651,584
  float* kvb = (float*)(ws + 159383552);    //  1,048,576  kv^T: [bh][e*64+d]
  u16* Weffx = (u16*)(ws + 160432128);      //  8,388,608
  u16* Weffc = (u16*)(ws + 168820736);      //  8,388,608
  // split-K partials (17 x 64 x 4096 f32 = 17.8 MB) alias Xb: proj_fused has
  // fully consumed Xb before kv_mfma runs.
  float* kvp = (float*)(ws + 0);

  cvt_all<<<25600, 256, 0, stream>>>(
      x, c, (const float*)d_in[2], (const float*)d_in[3], (const float*)d_in[4],
      (const float*)d_in[5], (const float*)d_in[6], (const float*)d_in[7],
      (const float*)d_in[8], (const float*)d_in[9], Xb, Cb, Wb);

  // all 6 QKV projections in one dispatch (Q row-major; K,V transposed)
  proj_fused<<<dim3(12, 68), 512, 65536, stream>>>(Xb, Cb, Wb, Qx, Qc, Kt, Vt, nc);
  // kv = K^T V per (b,h): split-K partials (plain stores), then reduce
  kv_mfma<<<dim3(64, 17), 256, 0, stream>>>(Kt, Vt, kvp);
  kv_reduce<<<256, 256, 0, stream>>>(kvp, kvb);
  // fold kv into output projections: Weff[b] = blockdiag(kv) applied to Wo
  weff_build<<<dim3(16, 64, 2), 256, 0, stream>>>(Wb + 6 * 1048576, Wb + 7 * 1048576,
                                                  kvb, Weffx, Weffc);
  // both output GEMMs in one dispatch, straight into d_out (fp32)
  out_fused<<<dim3(4, 68), 512, 65536, stream>>>(Qx, Qc, Weffx, Weffc, out);
}

// Round 9
// 392.130 us; speedup vs baseline: 1.0526x; 1.0526x over previous
//
#include <hip/hip_runtime.h>
#include <cstdint>

typedef unsigned int u32;
typedef unsigned short u16;
typedef float fx4 __attribute__((ext_vector_type(4)));
typedef __bf16 bfx8 __attribute__((ext_vector_type(8)));

// ---------- helpers ----------
__device__ __forceinline__ u16 f2bf(float f) {
  u32 u = __builtin_bit_cast(u32, f);
  u32 r = (u + 0x7fffu + ((u >> 16) & 1u)) >> 16;  // RNE
  return (u16)r;
}
__device__ __forceinline__ float bf2f(u16 v) {
  return __builtin_bit_cast(float, (u32)v << 16);
}
// async global->LDS, 16B per lane (gfx950). LDS dest = wave-uniform base + lane*16.
__device__ __forceinline__ void async_copy16(const void* g, void* l) {
  auto gp = reinterpret_cast<__attribute__((address_space(1))) void*>((uintptr_t)g);
  auto lp = reinterpret_cast<__attribute__((address_space(3))) void*>((uintptr_t)l);
  __builtin_amdgcn_global_load_lds(gp, lp, 16, 0, 0);
}

// ---------- fp32 -> bf16 conversion of x, c, 8 weights ----------
__global__ __launch_bounds__(256) void cvt_all(
    const float* __restrict__ x, const float* __restrict__ c,
    const float* __restrict__ w0, const float* __restrict__ w1,
    const float* __restrict__ w2, const float* __restrict__ w3,
    const float* __restrict__ w4, const float* __restrict__ w5,
    const float* __restrict__ w6, const float* __restrict__ w7,
    u16* __restrict__ xb, u16* __restrict__ cb, u16* __restrict__ wb) {
  const int i = blockIdx.x * 256 + threadIdx.x;  // float4 index
  const float* src;
  u16* dst;
  size_t off;
  if (i < 4194304) {            // x: 16777216 floats
    src = x; dst = xb; off = (size_t)i;
  } else if (i < 4456448) {     // c: 1048576 floats
    src = c; dst = cb; off = (size_t)(i - 4194304);
  } else {                      // 8 weights, 1048576 floats each
    const int r = i - 4456448;
    const int wsel = r >> 18;
    off = (size_t)(r & 262143);
    switch (wsel) {
      case 0: src = w0; break; case 1: src = w1; break;
      case 2: src = w2; break; case 3: src = w3; break;
      case 4: src = w4; break; case 5: src = w5; break;
      case 6: src = w6; break; default: src = w7; break;
    }
    dst = wb + (size_t)wsel * 1048576;
  }
  const fx4 v = *(const fx4*)(src + off * 4);
  uint2 o;
  o.x = (u32)f2bf(v[0]) | ((u32)f2bf(v[1]) << 16);
  o.y = (u32)f2bf(v[2]) | ((u32)f2bf(v[3]) << 16);
  *(uint2*)(dst + off * 4) = o;
}

// ---------- 256x256 tile GEMM core, K=1024, 8-phase schedule, 8 waves, 512 thr ----------
// (R4/R6-verified core: conflicts 557K, proj 152us.) Two K-tile buffers (U@0,
// V@32768 u16), each AKh0|AKh1|BKh0|BKh1 regions of 8192 u16. Packed 128B LDS
// rows, 8-chunk XOR swizzle via pre-swizzled global source. Per phase: {ds_read
// frag || stage 1 half-tile -> barrier -> lgkmcnt(0) -> setprio 16 MFMA ->
// [counted vmcnt] -> barrier}.
// R9 wait-thinning: steady iterations wait only at p3/p7 with vmcnt(4)
// (verified by stage->wait->read chain accounting: every region retired >=1
// phase before its read). Iteration 0 keeps vmcnt(8) at p1/p3/p5/p7 (prologue
// drain). Peeled last iteration: p3=4, p5=0.
#define GC_DSB(BUF, KS)                                                        \
  _Pragma("unroll") for (int i_ = 0; i_ < 4; ++i_) bfr[i_] =                   \
      *(const bfx8*)(lds + (BUF) + 16384 + (KS) * 8192 + wc * 2048 + i_ * 512 + aLane);
#define GC_DSA(BUF, KS, H)                                                     \
  _Pragma("unroll") for (int i_ = 0; i_ < 4; ++i_) af[i_] =                    \
      *(const bfx8*)(lds + (BUF) + (KS) * 8192 + wr * 4096 + (H) * 2048 + i_ * 512 + aLane);
#define GC_STA(REG, KCOL)                                                      \
  async_copy16(Aop + aOff0 + (KCOL), lds + (REG) + dst0);                      \
  async_copy16(Aop + aOff1 + (KCOL), lds + (REG) + dst1);
#define GC_STB(REG, KCOL)                                                      \
  async_copy16(Bop + bOff0 + (KCOL), lds + (REG) + dst0);                      \
  async_copy16(Bop + bOff1 + (KCOL), lds + (REG) + dst1);
#define GC_MFMA(H)                                                             \
  __builtin_amdgcn_s_setprio(1);                                               \
  _Pragma("unroll") for (int mi_ = 0; mi_ < 4; ++mi_)                          \
  _Pragma("unroll") for (int ni_ = 0; ni_ < 4; ++ni_)                          \
      acc[(H) * 4 + mi_][ni_] = __builtin_amdgcn_mfma_f32_16x16x32_bf16(       \
          af[mi_], bfr[ni_], acc[(H) * 4 + mi_][ni_], 0, 0, 0);                \
  __builtin_amdgcn_s_setprio(0);
#define GC_MID()                                                               \
  __builtin_amdgcn_s_barrier();                                                \
  asm volatile("s_waitcnt lgkmcnt(0)" ::: "memory");                           \
  __builtin_amdgcn_sched_barrier(0);
#define GC_END()                                                               \
  __builtin_amdgcn_s_barrier();                                                \
  __builtin_amdgcn_sched_barrier(0);

__device__ __forceinline__ void gemm256_core(
    const u16* __restrict__ Aop, const u16* __restrict__ Bop,
    long rowBase, long colBase, u16* lds, fx4 (&acc)[8][4]) {
  const int t = threadIdx.x;           // 0..511
  const int lane = t & 63;
  const int lr = lane & 15;
  const int quad = lane >> 4;
  const int w = t >> 6;                // 0..7
  const int wr = w >> 2;               // 0..1  (M half)
  const int wc = w & 3;                // 0..3  (N quarter)
  const int phys = (((lr & 1) << 2) | quad) ^ ((lr >> 1) & 7);
  const int aLane = ((lr >> 1) << 6) + (phys << 3);

  // staging inverse-swizzle map: chunks c = t, t+512 of a 16KB half-tile
  int aOff0, aOff1, bOff0, bOff1, dst0, dst1;
  {
    const int c0 = t;
    const int R0 = c0 >> 3;
    const int lg0 = (c0 & 7) ^ (R0 & 7);
    const int m0_ = 2 * R0 + (lg0 >> 2);
    const int g0 = lg0 & 3;
    aOff0 = (int)(rowBase + m0_) * 1024 + g0 * 8;
    bOff0 = (int)(colBase + m0_) * 1024 + g0 * 8;
    dst0 = c0 * 8;
    const int c1 = t + 512;
    const int R1 = c1 >> 3;
    const int lg1 = (c1 & 7) ^ (R1 & 7);
    const int m1_ = 2 * R1 + (lg1 >> 2);
    const int g1 = lg1 & 3;
    aOff1 = (int)(rowBase + m1_) * 1024 + g1 * 8;
    bOff1 = (int)(colBase + m1_) * 1024 + g1 * 8;
    dst1 = c1 * 8;
  }

  // prologue: stage kt0 (U, both K-halves) + kt1 Kh0 (V)
  GC_STA(0, 0) GC_STB(16384, 0) GC_STA(8192, 32) GC_STB(24576, 32)
  GC_STA(32768, 64) GC_STB(49152, 64)
  asm volatile("s_waitcnt vmcnt(8)" ::: "memory");  // U.Kh0 (A+B) landed
  __builtin_amdgcn_s_barrier();
  __builtin_amdgcn_sched_barrier(0);

  bfx8 bfr[4];
  for (int it = 0; it < 8; ++it) {
    const bool firstI = (it == 0);
    const bool lastI = (it == 7);
    const int k1 = (2 * it + 1) * 64 + 32;  // V.Kh1 of kt 2it+1 (always real)
    const int k2 = (2 * it + 2) * 64;       // U' Kh0
    const int k3 = k2 + 32;                 // U' Kh1
    const int k4 = (2 * it + 3) * 64;       // V' Kh0
    // p0: U h0 ks0 | stage V.AKh1
    { bfx8 af[4];
      GC_DSB(0, 0) GC_DSA(0, 0, 0)
      GC_STA(40960, k1)
      GC_MID() GC_MFMA(0) GC_END() }
    // p1: U h1 ks0 | stage V.BKh1 | vmcnt(8) first iter only (prologue drain)
    { bfx8 af[4];
      GC_DSA(0, 0, 1)
      GC_STB(57344, k1)
      GC_MID() GC_MFMA(1)
      if (firstI) { asm volatile("s_waitcnt vmcnt(8)" ::: "memory"); }
      GC_END() }
    // p2: U h0 ks1 | stage U'.AKh0
    { bfx8 af[4];
      GC_DSB(0, 1) GC_DSA(0, 1, 0)
      if (!lastI) { GC_STA(0, k2) }
      GC_MID() GC_MFMA(0) GC_END() }
    // p3: U h1 ks1 | stage U'.BKh0 | vmcnt: first=8, else=4
    { bfx8 af[4];
      GC_DSA(0, 1, 1)
      if (!lastI) { GC_STB(16384, k2) }
      GC_MID() GC_MFMA(1)
      if (firstI) { asm volatile("s_waitcnt vmcnt(8)" ::: "memory"); }
      else        { asm volatile("s_waitcnt vmcnt(4)" ::: "memory"); }
      GC_END() }
    // p4: V h0 ks0 | stage U'.AKh1
    { bfx8 af[4];
      GC_DSB(32768, 0) GC_DSA(32768, 0, 0)
      if (!lastI) { GC_STA(8192, k3) }
      GC_MID() GC_MFMA(0) GC_END() }
    // p5: V h1 ks0 | stage U'.BKh1 | vmcnt: first=8, last=0, else none
    { bfx8 af[4];
      GC_DSA(32768, 0, 1)
      if (!lastI) { GC_STB(24576, k3) }
      GC_MID() GC_MFMA(1)
      if (firstI)     { asm volatile("s_waitcnt vmcnt(8)" ::: "memory"); }
      else if (lastI) { asm volatile("s_waitcnt vmcnt(0)" ::: "memory"); }
      GC_END() }
    // p6: V h0 ks1 | stage V'.AKh0
    { bfx8 af[4];
      GC_DSB(32768, 1) GC_DSA(32768, 1, 0)
      if (!lastI) { GC_STA(32768, k4) }
      GC_MID() GC_MFMA(0) GC_END() }
    // p7: V h1 ks1 | stage V'.BKh0 | vmcnt: first=8, last=none, else 4
    { bfx8 af[4];
      GC_DSA(32768, 1, 1)
      if (!lastI) { GC_STB(49152, k4) }
      GC_MID() GC_MFMA(1)
      if (firstI)      { asm volatile("s_waitcnt vmcnt(8)" ::: "memory"); }
      else if (!lastI) { asm volatile("s_waitcnt vmcnt(4)" ::: "memory"); }
      GC_END() }
  }
}

// ---------- fused projections: all 6 QKV GEMMs in one dispatch ----------
// XCD chunked swizzle: work u = yy*12 + xx (A-panel-major); u = (bid%8)*102 +
// bid/8 -> each XCD owns a contiguous row range; A hits ONE L2. 816%8==0.
__global__ __launch_bounds__(512, 2) void proj_fused(
    const u16* __restrict__ Xb, const u16* __restrict__ Cb, const u16* __restrict__ Wb,
    u16* __restrict__ Qx, u16* __restrict__ Qc,
    u16* __restrict__ Kt, u16* __restrict__ Vt,
    const float* __restrict__ nc) {
  extern __shared__ __align__(16) u16 lds[];
  const int bid = (int)(blockIdx.y * 12 + blockIdx.x);
  const int u = (bid & 7) * 102 + (bid >> 3);
  const int yy = u / 12;
  const int xx = u - yy * 12;
  const bool isC = yy >= 64;
  const u16* A = isC ? Cb : Xb;
  const u16* Bw = Wb + (isC ? 3145728 : 0);  // c-stream weights at +3*1024*1024
  const long rowBase = (long)(isC ? yy - 64 : yy) * 256;
  const long colBase = (long)xx * 256;

  fx4 acc[8][4] = {};
  gemm256_core(A, Bw, rowBase, colBase, lds, acc);

  const int t = threadIdx.x;
  const int lane = t & 63;
  const int lr = lane & 15;
  const int quad = lane >> 4;
  const int w = t >> 6;
  const int wr = w >> 2;
  const int wc = w & 3;
  const long wRowBase = rowBase + wr * 128;

  const long col0 = colBase + wc * 64;   // 64-aligned: wave covers one head segment
  const int col64 = (int)(col0 >> 6);    // 0..47
  const int sel = col64 >> 4;            // 0=q, 1=k, 2=v  (uniform per block)
  const int h = col64 & 15;
  const int lcolBase = (int)(col0 & 1023);

  if (sel == 0) {
    // Q: per-row l2norm, row-major store (feeds out_fused A-operand)
    u16* dst = isC ? Qc : Qx;
#pragma unroll
    for (int mi = 0; mi < 8; ++mi) {
      float ss[4] = {0.f, 0.f, 0.f, 0.f};
#pragma unroll
      for (int ni = 0; ni < 4; ++ni)
#pragma unroll
        for (int r = 0; r < 4; ++r) ss[r] += acc[mi][ni][r] * acc[mi][ni][r];
#pragma unroll
      for (int off = 1; off < 16; off <<= 1)
#pragma unroll
        for (int r = 0; r < 4; ++r) ss[r] += __shfl_xor(ss[r], off, 64);
      float sc[4];
#pragma unroll
      for (int r = 0; r < 4; ++r) sc[r] = 1.f / fmaxf(sqrtf(ss[r]), 1e-12f);
#pragma unroll
      for (int ni = 0; ni < 4; ++ni) {
        const long col = lcolBase + ni * 16 + lr;
#pragma unroll
        for (int r = 0; r < 4; ++r) {
          const long row = wRowBase + mi * 16 + quad * 4 + r;
          dst[row * 1024 + col] = f2bf(acc[mi][ni][r] * sc[r]);
        }
      }
    }
  } else {
    // K (l2norm) / V (scale): per-wave LDS transpose -> Kt/Vt[b,h][d][0..4352)
    __syncthreads();  // full drain: seal gemm LDS reads before reuse
    u16* LT = lds + w * 8192;  // 16KB per wave: [d=64][128 n], n-group ^ (d&15)
    u16* T = (sel == 1) ? Kt : Vt;
    int b, nglob0;
    if (!isC) { b = (int)(wRowBase >> 12); nglob0 = (int)(wRowBase & 4095); }
    else      { b = (int)(wRowBase >> 8);  nglob0 = 4096 + (int)(wRowBase & 255); }
    u16* Tw = T + (size_t)(b * 16 + h) * 64 * 4352;
    const float vs = __expf(-8.3783908f / (1.f + __expf(-nc[h])));  // 4352^-sigmoid

#pragma unroll
    for (int mi = 0; mi < 8; ++mi) {
      float sc[4];
      if (sel == 1) {
        float ss[4] = {0.f, 0.f, 0.f, 0.f};
#pragma unroll
        for (int ni = 0; ni < 4; ++ni)
#pragma unroll
          for (int r = 0; r < 4; ++r) ss[r] += acc[mi][ni][r] * acc[mi][ni][r];
#pragma unroll
        for (int off = 1; off < 16; off <<= 1)
#pragma unroll
          for (int r = 0; r < 4; ++r) ss[r] += __shfl_xor(ss[r], off, 64);
#pragma unroll
        for (int r = 0; r < 4; ++r) sc[r] = 1.f / fmaxf(sqrtf(ss[r]), 1e-12f);
      } else {
#pragma unroll
        for (int r = 0; r < 4; ++r) sc[r] = vs;
      }
      const int g = mi * 2 + (quad >> 1);   // n-group (n_local = mi*16+quad*4+r)
      const int sub = (quad & 1) * 4;
#pragma unroll
      for (int ni = 0; ni < 4; ++ni) {
        const int d = ni * 16 + lr;
        uint2 o;
        o.x = (u32)f2bf(acc[mi][ni][0] * sc[0]) | ((u32)f2bf(acc[mi][ni][1] * sc[1]) << 16);
        o.y = (u32)f2bf(acc[mi][ni][2] * sc[2]) | ((u32)f2bf(acc[mi][ni][3] * sc[3]) << 16);
        *(uint2*)&LT[d * 128 + ((g ^ (d & 15)) << 3) + sub] = o;
      }
    }
    __syncthreads();  // uniform (sel uniform per block); orders LDS writes
    const int d = lane;
    u16* drow = Tw + (size_t)d * 4352 + nglob0;
#pragma unroll
    for (int j = 0; j < 16; ++j) {
      const uint4 qv = *(const uint4*)&LT[d * 128 + ((j ^ (d & 15)) << 3)];
      *(uint4*)&drow[j * 8] = qv;
    }
  }
}

// ---------- kv via MFMA, split-K partials (NO atomics) ----------
// grid (64, 17): block (bh, y) covers K-steps 4y..4y+3 (one 64-step per wave).
// Per-block 4-way LDS reduce, plain coalesced stores to kvp[y][bh].
__global__ __launch_bounds__(256) void kv_mfma(
    const u16* __restrict__ Kt, const u16* __restrict__ Vt, float* __restrict__ kvp) {
  __shared__ __align__(16) u16 TT[4][2][4096];  // per wave: K tile, V tile (64x64 u16)
  const int bh = blockIdx.x;
  const int t = threadIdx.x;
  const int w = t >> 6;
  const int lane = t & 63;
  const int lr = lane & 15;
  const int quad = lane >> 4;
  const u16* Ksrc = Kt + (size_t)bh * 64 * 4352;
  const u16* Vsrc = Vt + (size_t)bh * 64 * 4352;
  const int row8 = lane >> 3;
  const int gst = lane & 7;
  fx4 acc[4][4] = {};

  const int kbase = (blockIdx.y * 4 + w) * 64;  // this wave's K-step
#pragma unroll
  for (int i = 0; i < 8; ++i) {
    const int row = i * 8 + row8;
    const int col = ((gst ^ (row & 7)) << 3);
    const size_t go = (size_t)row * 4352 + kbase + col;
    async_copy16(Ksrc + go, &TT[w][0][i * 512 + lane * 8]);
    async_copy16(Vsrc + go, &TT[w][1][i * 512 + lane * 8]);
  }
  __syncthreads();
#pragma unroll
  for (int ks = 0; ks < 2; ++ks) {
    bfx8 af[4], bfr[4];
    const int g = ((ks * 4 + quad) ^ (lr & 7)) << 3;
#pragma unroll
    for (int i = 0; i < 4; ++i) af[i] = *(const bfx8*)&TT[w][0][(i * 16 + lr) * 64 + g];
#pragma unroll
    for (int i = 0; i < 4; ++i) bfr[i] = *(const bfx8*)&TT[w][1][(i * 16 + lr) * 64 + g];
#pragma unroll
    for (int mi = 0; mi < 4; ++mi)
#pragma unroll
      for (int ni = 0; ni < 4; ++ni)
        acc[mi][ni] =
            __builtin_amdgcn_mfma_f32_16x16x32_bf16(af[mi], bfr[ni], acc[mi][ni], 0, 0, 0);
  }
  __syncthreads();
  // per-wave partial C^T [e][d] f32, d-group swizzled; then 4-way reduce
  float* red = (float*)&TT[0][0][0];  // 16384 f32
  float* my = red + w * 4096;
#pragma unroll
  for (int mi = 0; mi < 4; ++mi)
#pragma unroll
    for (int ni = 0; ni < 4; ++ni) {
      const int e = ni * 16 + lr;
      const int dg = mi * 4 + quad;      // d = dg*4 + r, r consecutive in acc
      *(fx4*)&my[e * 64 + ((dg ^ (e & 15)) << 2)] = acc[mi][ni];
    }
  __syncthreads();
  float* outp = kvp + ((size_t)blockIdx.y * 64 + bh) * 4096;
#pragma unroll
  for (int j = 0; j < 4; ++j) {
    const int L = t * 16 + j * 4;        // flat [e][d] index
    const int e = L >> 6;
    const int dg = (L >> 2) & 15;
    const int addr = e * 64 + ((dg ^ (e & 15)) << 2);
    fx4 sv = *(const fx4*)&red[addr];
    sv += *(const fx4*)&red[4096 + addr];
    sv += *(const fx4*)&red[8192 + addr];
    sv += *(const fx4*)&red[12288 + addr];
    *(fx4*)&outp[L] = sv;
  }
}

// ---------- sum the 17 split-K partials: kvb[bh] = sum_y kvp[y][bh] ----------
__global__ __launch_bounds__(256) void kv_reduce(
    const float* __restrict__ kvp, float* __restrict__ kvb) {
  const int o = blockIdx.x * 256 + threadIdx.x;  // fx4 index, 65536 total
  const int bh = o >> 10;
  const int idx = (o & 1023) * 4;
  fx4 s = {0.f, 0.f, 0.f, 0.f};
#pragma unroll
  for (int y = 0; y < 17; ++y)
    s += *(const fx4*)&kvp[((size_t)y * 64 + bh) * 4096 + idx];
  *(fx4*)&kvb[(size_t)bh * 4096 + idx] = s;
}

// ---------- Weff[b][o, h*64+d] = sum_e Wo[o, h*64+e] * kv[b,h][d,e]  (bf16 out) ----------
// kvb holds kv transposed: kvb[bh][e*64+d].
__global__ __launch_bounds__(256) void weff_build(
    const u16* __restrict__ WoX, const u16* __restrict__ WoC,
    const float* __restrict__ kvb, u16* __restrict__ WeffX, u16* __restrict__ WeffC) {
  const int ot = blockIdx.x;
  const int bh = blockIdx.y;
  const int b = bh >> 4, h = bh & 15;
  const u16* Wo = blockIdx.z ? WoC : WoX;
  u16* outp = (blockIdx.z ? WeffC : WeffX) + (size_t)b * 1048576;

  __shared__ __align__(16) float kvT[64 * 64];  // [e][d] = kvb layout, direct copy
  __shared__ __align__(16) float WoT[64 * 64];  // [e][o_local]
  const int t = threadIdx.x;
#pragma unroll
  for (int j = 0; j < 4; ++j) {
    const int idx = (t + 256 * j) * 4;
    *(fx4*)&kvT[idx] = *(const fx4*)&kvb[(size_t)bh * 4096 + idx];
  }
#pragma unroll
  for (int j = 0; j < 2; ++j) {
    const int u = t + 256 * j;  // 512 groups of 8 bf16
    const int row = u >> 3;     // o_local
    const int e0 = (u & 7) * 8;
    const uint4 q = *(const uint4*)&Wo[(size_t)(ot * 64 + row) * 1024 + h * 64 + e0];
    WoT[(e0 + 0) * 64 + row] = bf2f((u16)(q.x & 0xffff));
    WoT[(e0 + 1) * 64 + row] = bf2f((u16)(q.x >> 16));
    WoT[(e0 + 2) * 64 + row] = bf2f((u16)(q.y & 0xffff));
    WoT[(e0 + 3) * 64 + row] = bf2f((u16)(q.y >> 16));
    WoT[(e0 + 4) * 64 + row] = bf2f((u16)(q.z & 0xffff));
    WoT[(e0 + 5) * 64 + row] = bf2f((u16)(q.z >> 16));
    WoT[(e0 + 6) * 64 + row] = bf2f((u16)(q.w & 0xffff));
    WoT[(e0 + 7) * 64 + row] = bf2f((u16)(q.w >> 16));
  }
  __syncthreads();
  const int ob = (t >> 4) * 4;  // o_local base
  const int db = (t & 15) * 4;  // d base
  float acc[4][4] = {};
#pragma unroll 4
  for (int e = 0; e < 64; ++e) {
    const fx4 wv = *(const fx4*)&WoT[e * 64 + ob];
    const fx4 kvv = *(const fx4*)&kvT[e * 64 + db];
#pragma unroll
    for (int i = 0; i < 4; ++i)
#pragma unroll
      for (int j = 0; j < 4; ++j)
        acc[i][j] += wv[i] * kvv[j];
  }
#pragma unroll
  for (int i = 0; i < 4; ++i)
#pragma unroll
    for (int j = 0; j < 4; ++j)
      outp[(size_t)(ot * 64 + ob + i) * 1024 + h * 64 + db + j] = f2bf(acc[i][j]);
}

// ---------- fused output GEMMs: out = q @ Weff[b]^T for x and c streams ----------
// XCD chunked swizzle: u = yt*4 + xx; u = (bid%8)*34 + bid/8 (272 % 8 == 0).
__global__ __launch_bounds__(512, 2) void out_fused(
    const u16* __restrict__ Qx, const u16* __restrict__ Qc,
    const u16* __restrict__ Wex, const u16* __restrict__ Wec,
    float* __restrict__ out) {
  extern __shared__ __align__(16) u16 lds[];
  const int bid = (int)(blockIdx.y * 4 + blockIdx.x);
  const int u = (bid & 7) * 34 + (bid >> 3);
  const int yt = u >> 2;
  const int xx = u & 3;
  const int b = yt / 17;
  const int l = yt - b * 17;
  const bool isC = (l == 16);
  const u16* A;
  const u16* Bw;
  float* C;
  long rowBase;
  if (!isC) {
    A = Qx + (size_t)b * 4194304;
    Bw = Wex + (size_t)b * 1048576;
    C = out + (size_t)b * 4194304;
    rowBase = (long)l * 256;
  } else {
    A = Qc + (size_t)b * 262144;
    Bw = Wec + (size_t)b * 1048576;
    C = out + 16777216 + (size_t)b * 262144;
    rowBase = 0;
  }
  const long colBase = (long)xx * 256;

  fx4 acc[8][4] = {};
  gemm256_core(A, Bw, rowBase, colBase, lds, acc);

  const int t = threadIdx.x;
  const int lane = t & 63;
  const int lr = lane & 15;
  const int quad = lane >> 4;
  const int w = t >> 6;
  const int wr = w >> 2;
  const int wc = w & 3;
#pragma unroll
  for (int mi = 0; mi < 8; ++mi)
#pragma unroll
    for (int ni = 0; ni < 4; ++ni) {
      const long col = colBase + wc * 64 + ni * 16 + lr;
#pragma unroll
      for (int r = 0; r < 4; ++r) {
        const long row = rowBase + wr * 128 + mi * 16 + quad * 4 + r;
        C[row * 1024 + col] = acc[mi][ni][r];
      }
    }
}

// ---------- launch ----------
extern "C" void kernel_launch(void* const* d_in, const int* in_sizes, int n_in,
                              void* d_out, int out_size, void* d_ws, size_t ws_size,
                              hipStream_t stream) {
  (void)in_sizes; (void)n_in; (void)out_size; (void)ws_size;
  const float* x = (const float*)d_in[0];
  const float* c = (const float*)d_in[1];
  const float* nc = (const float*)d_in[10];
  float* out = (float*)d_out;
  char* ws = (char*)d_ws;

  static bool attr_done = false;
  if (!attr_done) {
    hipFuncSetAttribute((const void*)proj_fused,
                        hipFuncAttributeMaxDynamicSharedMemorySize, 131072);
    hipFuncSetAttribute((const void*)out_fused,
                        hipFuncAttributeMaxDynamicSharedMemorySize, 131072);
    attr_done = true;
  }

  // workspace layout (bytes). total = 177,209,344
  u16* Xb = (u16*)(ws + 0);                 // 33,554,432
  u16* Cb = (u16*)(ws + 33554432);          //  2,097,152
  u16* Wb = (u16*)(ws + 35651584);          // 16,777,216 (8 weights bf16)
  u16* Qx = (u16*)(ws + 52428800);          // 33,554,432
  u16* Qc = (u16*)(ws + 85983232);          //  2,097,152
  u16* Kt = (u16*)(ws + 88080384);          // 35,651,584  [b,h][64 d][4352 n]
  u16* Vt = (u16*)(ws + 123731968);         // 35,651,584
  float* kvb = (float*)(ws + 159383552);    //  1,048,576  kv^T: [bh][e*64+d]
  u16* Weffx = (u16*)(ws + 160432128);      //  8,388,608
  u16* Weffc = (u16*)(ws + 168820736);      //  8,388,608
  // split-K partials (17 x 64 x 4096 f32 = 17.8 MB) alias Xb: proj_fused has
  // fully consumed Xb before kv_mfma runs.
  float* kvp = (float*)(ws + 0);

  cvt_all<<<25600, 256, 0, stream>>>(
      x, c, (const float*)d_in[2], (const float*)d_in[3], (const float*)d_in[4],
      (const float*)d_in[5], (const float*)d_in[6], (const float*)d_in[7],
      (const float*)d_in[8], (const float*)d_in[9], Xb, Cb, Wb);

  // all 6 QKV projections in one dispatch (Q row-major; K,V transposed)
  proj_fused<<<dim3(12, 68), 512, 131072, stream>>>(Xb, Cb, Wb, Qx, Qc, Kt, Vt, nc);
  // kv = K^T V per (b,h): split-K partials (plain stores), then reduce
  kv_mfma<<<dim3(64, 17), 256, 0, stream>>>(Kt, Vt, kvp);
  kv_reduce<<<256, 256, 0, stream>>>(kvp, kvb);
  // fold kv into output projections: Weff[b] = blockdiag(kv) applied to Wo
  weff_build<<<dim3(16, 64, 2), 256, 0, stream>>>(Wb + 6 * 1048576, Wb + 7 * 1048576,
                                                  kvb, Weffx, Weffc);
  // both output GEMMs in one dispatch, straight into d_out (fp32)
  out_fused<<<dim3(4, 68), 512, 131072, stream>>>(Qx, Qc, Weffx, Weffc, out);
}

// Round 10
// 387.315 us; speedup vs baseline: 1.0656x; 1.0124x over previous
//
#include <hip/hip_runtime.h>
#include <cstdint>

typedef unsigned int u32;
typedef unsigned short u16;
typedef float fx4 __attribute__((ext_vector_type(4)));
typedef __bf16 bfx8 __attribute__((ext_vector_type(8)));

// ---------- helpers ----------
__device__ __forceinline__ u16 f2bf(float f) {
  u32 u = __builtin_bit_cast(u32, f);
  u32 r = (u + 0x7fffu + ((u >> 16) & 1u)) >> 16;  // RNE
  return (u16)r;
}
__device__ __forceinline__ float bf2f(u16 v) {
  return __builtin_bit_cast(float, (u32)v << 16);
}
// async global->LDS, 16B per lane (gfx950). LDS dest = wave-uniform base + lane*16.
__device__ __forceinline__ void async_copy16(const void* g, void* l) {
  auto gp = reinterpret_cast<__attribute__((address_space(1))) void*>((uintptr_t)g);
  auto lp = reinterpret_cast<__attribute__((address_space(3))) void*>((uintptr_t)l);
  __builtin_amdgcn_global_load_lds(gp, lp, 16, 0, 0);
}

// ---------- fp32 -> bf16 conversion of x, c, 8 weights ----------
__global__ __launch_bounds__(256) void cvt_all(
    const float* __restrict__ x, const float* __restrict__ c,
    const float* __restrict__ w0, const float* __restrict__ w1,
    const float* __restrict__ w2, const float* __restrict__ w3,
    const float* __restrict__ w4, const float* __restrict__ w5,
    const float* __restrict__ w6, const float* __restrict__ w7,
    u16* __restrict__ xb, u16* __restrict__ cb, u16* __restrict__ wb) {
  const int i = blockIdx.x * 256 + threadIdx.x;  // float4 index
  const float* src;
  u16* dst;
  size_t off;
  if (i < 4194304) {            // x: 16777216 floats
    src = x; dst = xb; off = (size_t)i;
  } else if (i < 4456448) {     // c: 1048576 floats
    src = c; dst = cb; off = (size_t)(i - 4194304);
  } else {                      // 8 weights, 1048576 floats each
    const int r = i - 4456448;
    const int wsel = r >> 18;
    off = (size_t)(r & 262143);
    switch (wsel) {
      case 0: src = w0; break; case 1: src = w1; break;
      case 2: src = w2; break; case 3: src = w3; break;
      case 4: src = w4; break; case 5: src = w5; break;
      case 6: src = w6; break; default: src = w7; break;
    }
    dst = wb + (size_t)wsel * 1048576;
  }
  const fx4 v = *(const fx4*)(src + off * 4);
  uint2 o;
  o.x = (u32)f2bf(v[0]) | ((u32)f2bf(v[1]) << 16);
  o.y = (u32)f2bf(v[2]) | ((u32)f2bf(v[3]) << 16);
  *(uint2*)(dst + off * 4) = o;
}

// ---------- 256x256 tile GEMM core, K=1024, 8-phase schedule, 8 waves, 512 thr ----------
// (R4/R6/R9-verified: conflicts 557K, proj 152us.) Two K-tile buffers (U@0,
// V@32768 u16), each AKh0|AKh1|BKh0|BKh1 regions of 8192 u16. Packed 128B LDS
// rows, 8-chunk XOR swizzle via pre-swizzled global source. Steady iterations
// wait only at p3/p7 with vmcnt(4); iter0 keeps vmcnt(8); peel: p3=4, p5=0.
#define GC_DSB(BUF, KS)                                                        \
  _Pragma("unroll") for (int i_ = 0; i_ < 4; ++i_) bfr[i_] =                   \
      *(const bfx8*)(lds + (BUF) + 16384 + (KS) * 8192 + wc * 2048 + i_ * 512 + aLane);
#define GC_DSA(BUF, KS, H)                                                     \
  _Pragma("unroll") for (int i_ = 0; i_ < 4; ++i_) af[i_] =                    \
      *(const bfx8*)(lds + (BUF) + (KS) * 8192 + wr * 4096 + (H) * 2048 + i_ * 512 + aLane);
#define GC_STA(REG, KCOL)                                                      \
  async_copy16(Aop + aOff0 + (KCOL), lds + (REG) + dst0);                      \
  async_copy16(Aop + aOff1 + (KCOL), lds + (REG) + dst1);
#define GC_STB(REG, KCOL)                                                      \
  async_copy16(Bop + bOff0 + (KCOL), lds + (REG) + dst0);                      \
  async_copy16(Bop + bOff1 + (KCOL), lds + (REG) + dst1);
#define GC_MFMA(H)                                                             \
  __builtin_amdgcn_s_setprio(1);                                               \
  _Pragma("unroll") for (int mi_ = 0; mi_ < 4; ++mi_)                          \
  _Pragma("unroll") for (int ni_ = 0; ni_ < 4; ++ni_)                          \
      acc[(H) * 4 + mi_][ni_] = __builtin_amdgcn_mfma_f32_16x16x32_bf16(       \
          af[mi_], bfr[ni_], acc[(H) * 4 + mi_][ni_], 0, 0, 0);                \
  __builtin_amdgcn_s_setprio(0);
#define GC_MID()                                                               \
  __builtin_amdgcn_s_barrier();                                                \
  asm volatile("s_waitcnt lgkmcnt(0)" ::: "memory");                           \
  __builtin_amdgcn_sched_barrier(0);
#define GC_END()                                                               \
  __builtin_amdgcn_s_barrier();                                                \
  __builtin_amdgcn_sched_barrier(0);

__device__ __forceinline__ void gemm256_core(
    const u16* __restrict__ Aop, const u16* __restrict__ Bop,
    long rowBase, long colBase, u16* lds, fx4 (&acc)[8][4]) {
  const int t = threadIdx.x;           // 0..511
  const int lane = t & 63;
  const int lr = lane & 15;
  const int quad = lane >> 4;
  const int w = t >> 6;                // 0..7
  const int wr = w >> 2;               // 0..1  (M half)
  const int wc = w & 3;                // 0..3  (N quarter)
  const int phys = (((lr & 1) << 2) | quad) ^ ((lr >> 1) & 7);
  const int aLane = ((lr >> 1) << 6) + (phys << 3);

  // staging inverse-swizzle map: chunks c = t, t+512 of a 16KB half-tile
  int aOff0, aOff1, bOff0, bOff1, dst0, dst1;
  {
    const int c0 = t;
    const int R0 = c0 >> 3;
    const int lg0 = (c0 & 7) ^ (R0 & 7);
    const int m0_ = 2 * R0 + (lg0 >> 2);
    const int g0 = lg0 & 3;
    aOff0 = (int)(rowBase + m0_) * 1024 + g0 * 8;
    bOff0 = (int)(colBase + m0_) * 1024 + g0 * 8;
    dst0 = c0 * 8;
    const int c1 = t + 512;
    const int R1 = c1 >> 3;
    const int lg1 = (c1 & 7) ^ (R1 & 7);
    const int m1_ = 2 * R1 + (lg1 >> 2);
    const int g1 = lg1 & 3;
    aOff1 = (int)(rowBase + m1_) * 1024 + g1 * 8;
    bOff1 = (int)(colBase + m1_) * 1024 + g1 * 8;
    dst1 = c1 * 8;
  }

  // prologue: stage kt0 (U, both K-halves) + kt1 Kh0 (V)
  GC_STA(0, 0) GC_STB(16384, 0) GC_STA(8192, 32) GC_STB(24576, 32)
  GC_STA(32768, 64) GC_STB(49152, 64)
  asm volatile("s_waitcnt vmcnt(8)" ::: "memory");  // U.Kh0 (A+B) landed
  __builtin_amdgcn_s_barrier();
  __builtin_amdgcn_sched_barrier(0);

  bfx8 bfr[4];
  for (int it = 0; it < 8; ++it) {
    const bool firstI = (it == 0);
    const bool lastI = (it == 7);
    const int k1 = (2 * it + 1) * 64 + 32;  // V.Kh1 of kt 2it+1 (always real)
    const int k2 = (2 * it + 2) * 64;       // U' Kh0
    const int k3 = k2 + 32;                 // U' Kh1
    const int k4 = (2 * it + 3) * 64;       // V' Kh0
    // p0: U h0 ks0 | stage V.AKh1
    { bfx8 af[4];
      GC_DSB(0, 0) GC_DSA(0, 0, 0)
      GC_STA(40960, k1)
      GC_MID() GC_MFMA(0) GC_END() }
    // p1: U h1 ks0 | stage V.BKh1 | vmcnt(8) first iter only (prologue drain)
    { bfx8 af[4];
      GC_DSA(0, 0, 1)
      GC_STB(57344, k1)
      GC_MID() GC_MFMA(1)
      if (firstI) { asm volatile("s_waitcnt vmcnt(8)" ::: "memory"); }
      GC_END() }
    // p2: U h0 ks1 | stage U'.AKh0
    { bfx8 af[4];
      GC_DSB(0, 1) GC_DSA(0, 1, 0)
      if (!lastI) { GC_STA(0, k2) }
      GC_MID() GC_MFMA(0) GC_END() }
    // p3: U h1 ks1 | stage U'.BKh0 | vmcnt: first=8, else=4
    { bfx8 af[4];
      GC_DSA(0, 1, 1)
      if (!lastI) { GC_STB(16384, k2) }
      GC_MID() GC_MFMA(1)
      if (firstI) { asm volatile("s_waitcnt vmcnt(8)" ::: "memory"); }
      else        { asm volatile("s_waitcnt vmcnt(4)" ::: "memory"); }
      GC_END() }
    // p4: V h0 ks0 | stage U'.AKh1
    { bfx8 af[4];
      GC_DSB(32768, 0) GC_DSA(32768, 0, 0)
      if (!lastI) { GC_STA(8192, k3) }
      GC_MID() GC_MFMA(0) GC_END() }
    // p5: V h1 ks0 | stage U'.BKh1 | vmcnt: first=8, last=0, else none
    { bfx8 af[4];
      GC_DSA(32768, 0, 1)
      if (!lastI) { GC_STB(24576, k3) }
      GC_MID() GC_MFMA(1)
      if (firstI)     { asm volatile("s_waitcnt vmcnt(8)" ::: "memory"); }
      else if (lastI) { asm volatile("s_waitcnt vmcnt(0)" ::: "memory"); }
      GC_END() }
    // p6: V h0 ks1 | stage V'.AKh0
    { bfx8 af[4];
      GC_DSB(32768, 1) GC_DSA(32768, 1, 0)
      if (!lastI) { GC_STA(32768, k4) }
      GC_MID() GC_MFMA(0) GC_END() }
    // p7: V h1 ks1 | stage V'.BKh0 | vmcnt: first=8, last=none, else 4
    { bfx8 af[4];
      GC_DSA(32768, 1, 1)
      if (!lastI) { GC_STB(49152, k4) }
      GC_MID() GC_MFMA(1)
      if (firstI)      { asm volatile("s_waitcnt vmcnt(8)" ::: "memory"); }
      else if (!lastI) { asm volatile("s_waitcnt vmcnt(4)" ::: "memory"); }
      GC_END() }
  }
}

// ---------- fused projections: all 6 QKV GEMMs in one dispatch ----------
// XCD chunked swizzle: work u = yy*12 + xx (A-panel-major); u = (bid%8)*102 +
// bid/8 -> each XCD owns a contiguous row range; A hits ONE L2. 816%8==0.
__global__ __launch_bounds__(512, 2) void proj_fused(
    const u16* __restrict__ Xb, const u16* __restrict__ Cb, const u16* __restrict__ Wb,
    u16* __restrict__ Qx, u16* __restrict__ Qc,
    u16* __restrict__ Kt, u16* __restrict__ Vt,
    const float* __restrict__ nc) {
  extern __shared__ __align__(16) u16 lds[];
  const int bid = (int)(blockIdx.y * 12 + blockIdx.x);
  const int u = (bid & 7) * 102 + (bid >> 3);
  const int yy = u / 12;
  const int xx = u - yy * 12;
  const bool isC = yy >= 64;
  const u16* A = isC ? Cb : Xb;
  const u16* Bw = Wb + (isC ? 3145728 : 0);  // c-stream weights at +3*1024*1024
  const long rowBase = (long)(isC ? yy - 64 : yy) * 256;
  const long colBase = (long)xx * 256;

  fx4 acc[8][4] = {};
  gemm256_core(A, Bw, rowBase, colBase, lds, acc);

  const int t = threadIdx.x;
  const int lane = t & 63;
  const int lr = lane & 15;
  const int quad = lane >> 4;
  const int w = t >> 6;
  const int wr = w >> 2;
  const int wc = w & 3;
  const long wRowBase = rowBase + wr * 128;

  const long col0 = colBase + wc * 64;   // 64-aligned: wave covers one head segment
  const int col64 = (int)(col0 >> 6);    // 0..47
  const int sel = col64 >> 4;            // 0=q, 1=k, 2=v  (uniform per block)
  const int h = col64 & 15;
  const int lcolBase = (int)(col0 & 1023);

  if (sel == 0) {
    // Q: per-row l2norm, row-major store (feeds out_fused A-operand)
    u16* dst = isC ? Qc : Qx;
#pragma unroll
    for (int mi = 0; mi < 8; ++mi) {
      float ss[4] = {0.f, 0.f, 0.f, 0.f};
#pragma unroll
      for (int ni = 0; ni < 4; ++ni)
#pragma unroll
        for (int r = 0; r < 4; ++r) ss[r] += acc[mi][ni][r] * acc[mi][ni][r];
#pragma unroll
      for (int off = 1; off < 16; off <<= 1)
#pragma unroll
        for (int r = 0; r < 4; ++r) ss[r] += __shfl_xor(ss[r], off, 64);
      float sc[4];
#pragma unroll
      for (int r = 0; r < 4; ++r) sc[r] = 1.f / fmaxf(sqrtf(ss[r]), 1e-12f);
#pragma unroll
      for (int ni = 0; ni < 4; ++ni) {
        const long col = lcolBase + ni * 16 + lr;
#pragma unroll
        for (int r = 0; r < 4; ++r) {
          const long row = wRowBase + mi * 16 + quad * 4 + r;
          dst[row * 1024 + col] = f2bf(acc[mi][ni][r] * sc[r]);
        }
      }
    }
  } else {
    // K (l2norm) / V (scale): per-wave LDS transpose -> Kt/Vt[b,h][d][0..4352)
    __syncthreads();  // full drain: seal gemm LDS reads before reuse
    u16* LT = lds + w * 8192;  // 16KB per wave: [d=64][128 n], n-group ^ (d&15)
    u16* T = (sel == 1) ? Kt : Vt;
    int b, nglob0;
    if (!isC) { b = (int)(wRowBase >> 12); nglob0 = (int)(wRowBase & 4095); }
    else      { b = (int)(wRowBase >> 8);  nglob0 = 4096 + (int)(wRowBase & 255); }
    u16* Tw = T + (size_t)(b * 16 + h) * 64 * 4352;
    const float vs = __expf(-8.3783908f / (1.f + __expf(-nc[h])));  // 4352^-sigmoid

#pragma unroll
    for (int mi = 0; mi < 8; ++mi) {
      float sc[4];
      if (sel == 1) {
        float ss[4] = {0.f, 0.f, 0.f, 0.f};
#pragma unroll
        for (int ni = 0; ni < 4; ++ni)
#pragma unroll
          for (int r = 0; r < 4; ++r) ss[r] += acc[mi][ni][r] * acc[mi][ni][r];
#pragma unroll
        for (int off = 1; off < 16; off <<= 1)
#pragma unroll
          for (int r = 0; r < 4; ++r) ss[r] += __shfl_xor(ss[r], off, 64);
#pragma unroll
        for (int r = 0; r < 4; ++r) sc[r] = 1.f / fmaxf(sqrtf(ss[r]), 1e-12f);
      } else {
#pragma unroll
        for (int r = 0; r < 4; ++r) sc[r] = vs;
      }
      const int g = mi * 2 + (quad >> 1);   // n-group (n_local = mi*16+quad*4+r)
      const int sub = (quad & 1) * 4;
#pragma unroll
      for (int ni = 0; ni < 4; ++ni) {
        const int d = ni * 16 + lr;
        uint2 o;
        o.x = (u32)f2bf(acc[mi][ni][0] * sc[0]) | ((u32)f2bf(acc[mi][ni][1] * sc[1]) << 16);
        o.y = (u32)f2bf(acc[mi][ni][2] * sc[2]) | ((u32)f2bf(acc[mi][ni][3] * sc[3]) << 16);
        *(uint2*)&LT[d * 128 + ((g ^ (d & 15)) << 3) + sub] = o;
      }
    }
    __syncthreads();  // uniform (sel uniform per block); orders LDS writes
    const int d = lane;
    u16* drow = Tw + (size_t)d * 4352 + nglob0;
#pragma unroll
    for (int j = 0; j < 16; ++j) {
      const uint4 qv = *(const uint4*)&LT[d * 128 + ((j ^ (d & 15)) << 3)];
      *(uint4*)&drow[j * 8] = qv;
    }
  }
}

// ---------- 128x256 tile core for out_fused: BK=64, 2 phases/K-tile ----------
// 8 waves (2M x 4N), per-wave 64x64 out, acc[4][4] = 64 regs. LDS 96KB: 2 bufs
// x {A.ks0 8KB | A.ks1 8KB | B.ks0 16KB | B.ks1 16KB}. ks-split staging: phase
// pX of tile t stages tile t+1's ksX regions (3 loads) -> counted vmcnt(3) at
// EVERY phase end (retires the regions needed 2 phases later; cover ~2 phases
// > HBM latency; never 0 except the peeled tail). Same packed-row XOR swizzle.
__device__ __forceinline__ void gemm128_core(
    const u16* __restrict__ Aop, const u16* __restrict__ Bop,
    long rowBase, long colBase, u16* lds, fx4 (&acc)[4][4]) {
  const int t = threadIdx.x;           // 0..511
  const int lane = t & 63;
  const int lr = lane & 15;
  const int quad = lane >> 4;
  const int w = t >> 6;
  const int wr = w >> 2;               // 0..1 (M half: 64 rows)
  const int wc = w & 3;                // 0..3 (N quarter: 64 cols)
  const int phys = (((lr & 1) << 2) | quad) ^ ((lr >> 1) & 7);
  const int aLane = ((lr >> 1) << 6) + (phys << 3);

  // staging inverse-swizzle: A = 1 chunk (c=t, 8KB region), B = 2 (t, t+512)
  int aOffA, bOffB0, bOffB1, dstA, dstB0, dstB1;
  {
    const int c0 = t;                       // A: R in [0,64), m in [0,128)
    const int RA = c0 >> 3;
    const int lgA = (c0 & 7) ^ (RA & 7);
    aOffA = (int)(rowBase + 2 * RA + (lgA >> 2)) * 1024 + (lgA & 3) * 8;
    dstA = c0 * 8;
    const int RB0 = c0 >> 3;                // B chunk 0: same c=t, m in [0,256)
    const int lgB0 = (c0 & 7) ^ (RB0 & 7);
    bOffB0 = (int)(colBase + 2 * RB0 + (lgB0 >> 2)) * 1024 + (lgB0 & 3) * 8;
    dstB0 = c0 * 8;
    const int c1 = t + 512;
    const int RB1 = c1 >> 3;
    const int lgB1 = (c1 & 7) ^ (RB1 & 7);
    bOffB1 = (int)(colBase + 2 * RB1 + (lgB1 >> 2)) * 1024 + (lgB1 & 3) * 8;
    dstB1 = c1 * 8;
  }

#define O_ST(QB, KT, KS)                                                       \
  async_copy16(Aop + aOffA + (KT) * 64 + (KS) * 32, lds + (QB) + (KS) * 4096 + dstA); \
  async_copy16(Bop + bOffB0 + (KT) * 64 + (KS) * 32, lds + (QB) + 8192 + (KS) * 8192 + dstB0); \
  async_copy16(Bop + bOffB1 + (KT) * 64 + (KS) * 32, lds + (QB) + 8192 + (KS) * 8192 + dstB1);
#define O_DS(QB, KS)                                                           \
  _Pragma("unroll") for (int i_ = 0; i_ < 4; ++i_) af[i_] =                    \
      *(const bfx8*)(lds + (QB) + (KS) * 4096 + wr * 2048 + i_ * 512 + aLane); \
  _Pragma("unroll") for (int i_ = 0; i_ < 4; ++i_) bfr[i_] =                   \
      *(const bfx8*)(lds + (QB) + 8192 + (KS) * 8192 + wc * 2048 + i_ * 512 + aLane);
#define O_MFMA()                                                               \
  __builtin_amdgcn_s_setprio(1);                                               \
  _Pragma("unroll") for (int mi_ = 0; mi_ < 4; ++mi_)                          \
  _Pragma("unroll") for (int ni_ = 0; ni_ < 4; ++ni_)                          \
      acc[mi_][ni_] = __builtin_amdgcn_mfma_f32_16x16x32_bf16(                 \
          af[mi_], bfr[ni_], acc[mi_][ni_], 0, 0, 0);                          \
  __builtin_amdgcn_s_setprio(0);

  // prologue: stage tile0 ks0 + ks1 (6 loads); wait ks0 (3 left)
  O_ST(0, 0, 0) O_ST(0, 0, 1)
  asm volatile("s_waitcnt vmcnt(3)" ::: "memory");
  __builtin_amdgcn_s_barrier();
  __builtin_amdgcn_sched_barrier(0);

  for (int kt = 0; kt < 16; ++kt) {
    const int qb = (kt & 1) * 24576;
    const int nq = ((kt + 1) & 1) * 24576;
    const bool lastK = (kt == 15);
    // p0 (ks0): reads {A.ks0,B.ks0} | stage t+1 ks0
    { bfx8 af[4], bfr[4];
      O_DS(qb, 0)
      if (!lastK) { O_ST(nq, kt + 1, 0) }
      __builtin_amdgcn_s_barrier();
      asm volatile("s_waitcnt lgkmcnt(0)" ::: "memory");
      __builtin_amdgcn_sched_barrier(0);
      O_MFMA()
      __builtin_amdgcn_sched_barrier(0);
      if (lastK) { asm volatile("s_waitcnt vmcnt(0)" ::: "memory"); }
      else       { asm volatile("s_waitcnt vmcnt(3)" ::: "memory"); }
      __builtin_amdgcn_s_barrier();
      __builtin_amdgcn_sched_barrier(0); }
    // p1 (ks1): reads {A.ks1,B.ks1} | stage t+1 ks1
    { bfx8 af[4], bfr[4];
      O_DS(qb, 1)
      if (!lastK) { O_ST(nq, kt + 1, 1) }
      __builtin_amdgcn_s_barrier();
      asm volatile("s_waitcnt lgkmcnt(0)" ::: "memory");
      __builtin_amdgcn_sched_barrier(0);
      O_MFMA()
      __builtin_amdgcn_sched_barrier(0);
      if (!lastK) { asm volatile("s_waitcnt vmcnt(3)" ::: "memory"); }
      __builtin_amdgcn_s_barrier();
      __builtin_amdgcn_sched_barrier(0); }
  }
#undef O_ST
#undef O_DS
#undef O_MFMA
}

// ---------- kv via MFMA, split-K partials (NO atomics) ----------
// grid (64, 17): block (bh, y) covers K-steps 4y..4y+3 (one 64-step per wave).
// Per-block 4-way LDS reduce, plain coalesced stores to kvp[y][bh].
__global__ __launch_bounds__(256) void kv_mfma(
    const u16* __restrict__ Kt, const u16* __restrict__ Vt, float* __restrict__ kvp) {
  __shared__ __align__(16) u16 TT[4][2][4096];  // per wave: K tile, V tile (64x64 u16)
  const int bh = blockIdx.x;
  const int t = threadIdx.x;
  const int w = t >> 6;
  const int lane = t & 63;
  const int lr = lane & 15;
  const int quad = lane >> 4;
  const u16* Ksrc = Kt + (size_t)bh * 64 * 4352;
  const u16* Vsrc = Vt + (size_t)bh * 64 * 4352;
  const int row8 = lane >> 3;
  const int gst = lane & 7;
  fx4 acc[4][4] = {};

  const int kbase = (blockIdx.y * 4 + w) * 64;  // this wave's K-step
#pragma unroll
  for (int i = 0; i < 8; ++i) {
    const int row = i * 8 + row8;
    const int col = ((gst ^ (row & 7)) << 3);
    const size_t go = (size_t)row * 4352 + kbase + col;
    async_copy16(Ksrc + go, &TT[w][0][i * 512 + lane * 8]);
    async_copy16(Vsrc + go, &TT[w][1][i * 512 + lane * 8]);
  }
  __syncthreads();
#pragma unroll
  for (int ks = 0; ks < 2; ++ks) {
    bfx8 af[4], bfr[4];
    const int g = ((ks * 4 + quad) ^ (lr & 7)) << 3;
#pragma unroll
    for (int i = 0; i < 4; ++i) af[i] = *(const bfx8*)&TT[w][0][(i * 16 + lr) * 64 + g];
#pragma unroll
    for (int i = 0; i < 4; ++i) bfr[i] = *(const bfx8*)&TT[w][1][(i * 16 + lr) * 64 + g];
#pragma unroll
    for (int mi = 0; mi < 4; ++mi)
#pragma unroll
      for (int ni = 0; ni < 4; ++ni)
        acc[mi][ni] =
            __builtin_amdgcn_mfma_f32_16x16x32_bf16(af[mi], bfr[ni], acc[mi][ni], 0, 0, 0);
  }
  __syncthreads();
  // per-wave partial C^T [e][d] f32, d-group swizzled; then 4-way reduce
  float* red = (float*)&TT[0][0][0];  // 16384 f32
  float* my = red + w * 4096;
#pragma unroll
  for (int mi = 0; mi < 4; ++mi)
#pragma unroll
    for (int ni = 0; ni < 4; ++ni) {
      const int e = ni * 16 + lr;
      const int dg = mi * 4 + quad;      // d = dg*4 + r, r consecutive in acc
      *(fx4*)&my[e * 64 + ((dg ^ (e & 15)) << 2)] = acc[mi][ni];
    }
  __syncthreads();
  float* outp = kvp + ((size_t)blockIdx.y * 64 + bh) * 4096;
#pragma unroll
  for (int j = 0; j < 4; ++j) {
    const int L = t * 16 + j * 4;        // flat [e][d] index
    const int e = L >> 6;
    const int dg = (L >> 2) & 15;
    const int addr = e * 64 + ((dg ^ (e & 15)) << 2);
    fx4 sv = *(const fx4*)&red[addr];
    sv += *(const fx4*)&red[4096 + addr];
    sv += *(const fx4*)&red[8192 + addr];
    sv += *(const fx4*)&red[12288 + addr];
    *(fx4*)&outp[L] = sv;
  }
}

// ---------- sum the 17 split-K partials: kvb[bh] = sum_y kvp[y][bh] ----------
__global__ __launch_bounds__(256) void kv_reduce(
    const float* __restrict__ kvp, float* __restrict__ kvb) {
  const int o = blockIdx.x * 256 + threadIdx.x;  // fx4 index, 65536 total
  const int bh = o >> 10;
  const int idx = (o & 1023) * 4;
  fx4 s = {0.f, 0.f, 0.f, 0.f};
#pragma unroll
  for (int y = 0; y < 17; ++y)
    s += *(const fx4*)&kvp[((size_t)y * 64 + bh) * 4096 + idx];
  *(fx4*)&kvb[(size_t)bh * 4096 + idx] = s;
}

// ---------- Weff[b][o, h*64+d] = sum_e Wo[o, h*64+e] * kv[b,h][d,e]  (bf16 out) ----------
// kvb holds kv transposed: kvb[bh][e*64+d].
__global__ __launch_bounds__(256) void weff_build(
    const u16* __restrict__ WoX, const u16* __restrict__ WoC,
    const float* __restrict__ kvb, u16* __restrict__ WeffX, u16* __restrict__ WeffC) {
  const int ot = blockIdx.x;
  const int bh = blockIdx.y;
  const int b = bh >> 4, h = bh & 15;
  const u16* Wo = blockIdx.z ? WoC : WoX;
  u16* outp = (blockIdx.z ? WeffC : WeffX) + (size_t)b * 1048576;

  __shared__ __align__(16) float kvT[64 * 64];  // [e][d] = kvb layout, direct copy
  __shared__ __align__(16) float WoT[64 * 64];  // [e][o_local]
  const int t = threadIdx.x;
#pragma unroll
  for (int j = 0; j < 4; ++j) {
    const int idx = (t + 256 * j) * 4;
    *(fx4*)&kvT[idx] = *(const fx4*)&kvb[(size_t)bh * 4096 + idx];
  }
#pragma unroll
  for (int j = 0; j < 2; ++j) {
    const int u = t + 256 * j;  // 512 groups of 8 bf16
    const int row = u >> 3;     // o_local
    const int e0 = (u & 7) * 8;
    const uint4 q = *(const uint4*)&Wo[(size_t)(ot * 64 + row) * 1024 + h * 64 + e0];
    WoT[(e0 + 0) * 64 + row] = bf2f((u16)(q.x & 0xffff));
    WoT[(e0 + 1) * 64 + row] = bf2f((u16)(q.x >> 16));
    WoT[(e0 + 2) * 64 + row] = bf2f((u16)(q.y & 0xffff));
    WoT[(e0 + 3) * 64 + row] = bf2f((u16)(q.y >> 16));
    WoT[(e0 + 4) * 64 + row] = bf2f((u16)(q.z & 0xffff));
    WoT[(e0 + 5) * 64 + row] = bf2f((u16)(q.z >> 16));
    WoT[(e0 + 6) * 64 + row] = bf2f((u16)(q.w & 0xffff));
    WoT[(e0 + 7) * 64 + row] = bf2f((u16)(q.w >> 16));
  }
  __syncthreads();
  const int ob = (t >> 4) * 4;  // o_local base
  const int db = (t & 15) * 4;  // d base
  float acc[4][4] = {};
#pragma unroll 4
  for (int e = 0; e < 64; ++e) {
    const fx4 wv = *(const fx4*)&WoT[e * 64 + ob];
    const fx4 kvv = *(const fx4*)&kvT[e * 64 + db];
#pragma unroll
    for (int i = 0; i < 4; ++i)
#pragma unroll
      for (int j = 0; j < 4; ++j)
        acc[i][j] += wv[i] * kvv[j];
  }
#pragma unroll
  for (int i = 0; i < 4; ++i)
#pragma unroll
    for (int j = 0; j < 4; ++j)
      outp[(size_t)(ot * 64 + ob + i) * 1024 + h * 64 + db + j] = f2bf(acc[i][j]);
}

// ---------- fused output GEMMs (128x256 tiles): out = q @ Weff[b]^T ----------
// 544 blocks (136 yt x 4 xx), 2.125 rounds of ~half-size blocks (vs 272 at 1.06
// rounds of full-size: ~47% idle). XCD swizzle u=(bid%8)*68+bid/8 (544%8==0).
__global__ __launch_bounds__(512, 2) void out_fused(
    const u16* __restrict__ Qx, const u16* __restrict__ Qc,
    const u16* __restrict__ Wex, const u16* __restrict__ Wec,
    float* __restrict__ out) {
  extern __shared__ __align__(16) u16 lds[];
  const int bid = (int)(blockIdx.y * 4 + blockIdx.x);
  const int u = (bid & 7) * 68 + (bid >> 3);
  const int yt = u >> 2;                // 0..135
  const int xx = u & 3;
  const int b = yt / 34;
  const int l = yt - b * 34;
  const bool isC = (l >= 32);
  const u16* A;
  const u16* Bw;
  float* C;
  long rowBase;
  if (!isC) {
    A = Qx + (size_t)b * 4194304;
    Bw = Wex + (size_t)b * 1048576;
    C = out + (size_t)b * 4194304;
    rowBase = (long)l * 128;
  } else {
    A = Qc + (size_t)b * 262144;
    Bw = Wec + (size_t)b * 1048576;
    C = out + 16777216 + (size_t)b * 262144;
    rowBase = (long)(l - 32) * 128;
  }
  const long colBase = (long)xx * 256;

  fx4 acc[4][4] = {};
  gemm128_core(A, Bw, rowBase, colBase, lds, acc);

  const int t = threadIdx.x;
  const int lane = t & 63;
  const int lr = lane & 15;
  const int quad = lane >> 4;
  const int w = t >> 6;
  const int wr = w >> 2;
  const int wc = w & 3;
#pragma unroll
  for (int mi = 0; mi < 4; ++mi)
#pragma unroll
    for (int ni = 0; ni < 4; ++ni) {
      const long col = colBase + wc * 64 + ni * 16 + lr;
#pragma unroll
      for (int r = 0; r < 4; ++r) {
        const long row = rowBase + wr * 64 + mi * 16 + quad * 4 + r;
        C[row * 1024 + col] = acc[mi][ni][r];
      }
    }
}

// ---------- launch ----------
extern "C" void kernel_launch(void* const* d_in, const int* in_sizes, int n_in,
                              void* d_out, int out_size, void* d_ws, size_t ws_size,
                              hipStream_t stream) {
  (void)in_sizes; (void)n_in; (void)out_size; (void)ws_size;
  const float* x = (const float*)d_in[0];
  const float* c = (const float*)d_in[1];
  const float* nc = (const float*)d_in[10];
  float* out = (float*)d_out;
  char* ws = (char*)d_ws;

  static bool attr_done = false;
  if (!attr_done) {
    hipFuncSetAttribute((const void*)proj_fused,
                        hipFuncAttributeMaxDynamicSharedMemorySize, 131072);
    hipFuncSetAttribute((const void*)out_fused,
                        hipFuncAttributeMaxDynamicSharedMemorySize, 98304);
    attr_done = true;
  }

  // workspace layout (bytes). total = 177,209,344
  u16* Xb = (u16*)(ws + 0);                 // 33,554,432
  u16* Cb = (u16*)(ws + 33554432);          //  2,097,152
  u16* Wb = (u16*)(ws + 35651584);          // 16,777,216 (8 weights bf16)
  u16* Qx = (u16*)(ws + 52428800);          // 33,554,432
  u16* Qc = (u16*)(ws + 85983232);          //  2,097,152
  u16* Kt = (u16*)(ws + 88080384);          // 35,651,584  [b,h][64 d][4352 n]
  u16* Vt = (u16*)(ws + 123731968);         // 35,651,584
  float* kvb = (float*)(ws + 159383552);    //  1,048,576  kv^T: [bh][e*64+d]
  u16* Weffx = (u16*)(ws + 160432128);      //  8,388,608
  u16* Weffc = (u16*)(ws + 168820736);      //  8,388,608
  // split-K partials (17 x 64 x 4096 f32 = 17.8 MB) alias Xb: proj_fused has
  // fully consumed Xb before kv_mfma runs.
  float* kvp = (float*)(ws + 0);

  cvt_all<<<25600, 256, 0, stream>>>(
      x, c, (const float*)d_in[2], (const float*)d_in[3], (const float*)d_in[4],
      (const float*)d_in[5], (const float*)d_in[6], (const float*)d_in[7],
      (const float*)d_in[8], (const float*)d_in[9], Xb, Cb, Wb);

  // all 6 QKV projections in one dispatch (Q row-major; K,V transposed)
  proj_fused<<<dim3(12, 68), 512, 131072, stream>>>(Xb, Cb, Wb, Qx, Qc, Kt, Vt, nc);
  // kv = K^T V per (b,h): split-K partials (plain stores), then reduce
  kv_mfma<<<dim3(64, 17), 256, 0, stream>>>(Kt, Vt, kvp);
  kv_reduce<<<256, 256, 0, stream>>>(kvp, kvb);
  // fold kv into output projections: Weff[b] = blockdiag(kv) applied to Wo
  weff_build<<<dim3(16, 64, 2), 256, 0, stream>>>(Wb + 6 * 1048576, Wb + 7 * 1048576,
                                                  kvb, Weffx, Weffc);
  // both output GEMMs in one dispatch (128x256 tiles), straight into d_out
  out_fused<<<dim3(4, 136), 512, 98304, stream>>>(Qx, Qc, Weffx, Weffc, out);
}